// Round 1
// baseline (404.199 us; speedup 1.0000x reference)
//
#include <hip/hip_runtime.h>

#define B_     16
#define CIN_   256
#define D_     256
#define HEADS_ 8
#define N_     32
#define H_     56
#define W_     56
#define L_     3136   // 56*56

// ---------------------------------------------------------------------------
// Kernel 1: fused K = Wk @ x, V = Wv @ x   (per-batch GEMM 256x256 * 256x3136)
// 64(d) x 64(l) tile, K-chunk 16, 256 threads, 4x4 register block per thread,
// both outputs share the staged x tile.
// ---------------------------------------------------------------------------
__global__ __launch_bounds__(256) void gemm_kv_kernel(
    const float* __restrict__ x, const float* __restrict__ Wk,
    const float* __restrict__ Wv, float* __restrict__ Ko,
    float* __restrict__ Vo)
{
    __shared__ float xs[16][64];
    __shared__ float wks[16][64];
    __shared__ float wvs[16][64];

    const int b  = blockIdx.z;
    const int d0 = blockIdx.y * 64;
    const int l0 = blockIdx.x * 64;
    const int tid = threadIdx.x;
    const int tx = tid & 15;   // l sub-tile
    const int ty = tid >> 4;   // d sub-tile

    const float* xb = x + (size_t)b * CIN_ * L_;

    float aK[4][4] = {{0.f}};
    float aV[4][4] = {{0.f}};

    const int xr = tid >> 4;          // 0..15 : c row of x tile
    const int xc = (tid & 15) * 4;    // col
    const int wr = tid >> 2;          // 0..63 : d row of W tile
    const int wc = (tid & 3) * 4;     // c col

    for (int c0 = 0; c0 < CIN_; c0 += 16) {
        float4 xv = *(const float4*)(xb + (size_t)(c0 + xr) * L_ + (l0 + xc));
        float4 kv = *(const float4*)(Wk + (d0 + wr) * CIN_ + (c0 + wc));
        float4 vv = *(const float4*)(Wv + (d0 + wr) * CIN_ + (c0 + wc));

        __syncthreads();   // previous iteration's reads done
        *(float4*)&xs[xr][xc] = xv;
        wks[wc + 0][wr] = kv.x; wks[wc + 1][wr] = kv.y;
        wks[wc + 2][wr] = kv.z; wks[wc + 3][wr] = kv.w;
        wvs[wc + 0][wr] = vv.x; wvs[wc + 1][wr] = vv.y;
        wvs[wc + 2][wr] = vv.z; wvs[wc + 3][wr] = vv.w;
        __syncthreads();

#pragma unroll
        for (int c = 0; c < 16; ++c) {
            float4 a  = *(const float4*)&xs[c][tx * 4];
            float4 bk = *(const float4*)&wks[c][ty * 4];
            float4 bv = *(const float4*)&wvs[c][ty * 4];
            const float aj[4] = {a.x, a.y, a.z, a.w};
            const float bkj[4] = {bk.x, bk.y, bk.z, bk.w};
            const float bvj[4] = {bv.x, bv.y, bv.z, bv.w};
#pragma unroll
            for (int i = 0; i < 4; ++i)
#pragma unroll
                for (int j = 0; j < 4; ++j) {
                    aK[i][j] = fmaf(bkj[i], aj[j], aK[i][j]);
                    aV[i][j] = fmaf(bvj[i], aj[j], aV[i][j]);
                }
        }
    }

#pragma unroll
    for (int i = 0; i < 4; ++i) {
        const int d = d0 + ty * 4 + i;
        const size_t off = ((size_t)b * D_ + d) * L_ + l0 + tx * 4;
        *(float4*)(Ko + off) = make_float4(aK[i][0], aK[i][1], aK[i][2], aK[i][3]);
        *(float4*)(Vo + off) = make_float4(aV[i][0], aV[i][1], aV[i][2], aV[i][3]);
    }
}

// ---------------------------------------------------------------------------
// Kernel 2: S[b,h,p] = sum_n q[b, h*32+n] * K[b, h*32+n, p]
// ---------------------------------------------------------------------------
__global__ __launch_bounds__(64) void qk_s_kernel(
    const float* __restrict__ Ko, const float* __restrict__ q,
    float* __restrict__ S)
{
    const int p = blockIdx.x * 64 + threadIdx.x;
    const int h = blockIdx.y;
    const int b = blockIdx.z;
    const float* kp = Ko + ((size_t)b * D_ + h * N_) * L_ + p;
    const float* qp = q + b * D_ + h * N_;
    float acc = 0.f;
#pragma unroll
    for (int n = 0; n < N_; ++n)
        acc = fmaf(qp[n], kp[(size_t)n * L_], acc);
    S[((size_t)b * HEADS_ + h) * L_ + p] = acc;
}

// ---------------------------------------------------------------------------
// Kernel 3: softmax over the 9 shifted S values (+pos bias), then
// out_mid[b, h*32+n, l] = scale * sum_k w_k(l) * V[b, h*32+n, l+off_k].
// One thread = 4 consecutive l in one image row, all 32 n of one head.
// ---------------------------------------------------------------------------
__global__ __launch_bounds__(256) void attend_kernel(
    const float* __restrict__ S, const float* __restrict__ V,
    const float* __restrict__ pos_emb, const float* __restrict__ Wlin,
    float* __restrict__ Om)
{
    const int t   = blockIdx.x * 256 + threadIdx.x;   // 0 .. 100351
    const int bh  = t / 784;                          // 784 quads per (b,h)
    const int qid = t - bh * 784;
    const int b   = bh >> 3;
    const int h   = bh & 7;
    const int y   = qid / 14;
    const int x0  = (qid - y * 14) * 4;

    const float scale = Wlin[0] + Wlin[1] + Wlin[2] + Wlin[3];
    const float pe0 = pos_emb[0], pe1 = pos_emb[1], pe2 = pos_emb[2];
    const float pe3 = pos_emb[3], pe4 = pos_emb[4];
    // REL = {0,1,2, 1,2,3, 2,3,4}
    const float bias[9] = {pe0, pe1, pe2, pe1, pe2, pe3, pe2, pe3, pe4};

    // gather S: 3 rows x 6 cols around [y, x0..x0+3]; OOB -> 0 (padded K = 0)
    float sl[3][6];
    const float* Sb = S + (size_t)bh * L_;
#pragma unroll
    for (int dy = 0; dy < 3; ++dy) {
        const int r = y + dy - 1;
        float vm = 0.f, vp = 0.f;
        float4 c = make_float4(0.f, 0.f, 0.f, 0.f);
        if (r >= 0 && r < H_) {
            const float* row = Sb + r * W_ + x0;
            c = *(const float4*)row;
            if (x0 > 0)       vm = row[-1];
            if (x0 + 4 < W_)  vp = row[4];
        }
        sl[dy][0] = vm; sl[dy][1] = c.x; sl[dy][2] = c.y;
        sl[dy][3] = c.z; sl[dy][4] = c.w; sl[dy][5] = vp;
    }

    // softmax over k for each of the 4 positions
    float w[9][4];
#pragma unroll
    for (int j = 0; j < 4; ++j) {
        float lg[9];
        float m = -1e30f;
#pragma unroll
        for (int kh = 0; kh < 3; ++kh)
#pragma unroll
            for (int kw = 0; kw < 3; ++kw) {
                const float vv = sl[kh][j + kw] + bias[kh * 3 + kw];
                lg[kh * 3 + kw] = vv;
                m = fmaxf(m, vv);
            }
        float s = 0.f;
#pragma unroll
        for (int k = 0; k < 9; ++k) { lg[k] = __expf(lg[k] - m); s += lg[k]; }
        const float inv = scale / s;
#pragma unroll
        for (int k = 0; k < 9; ++k) w[k][j] = lg[k] * inv;
    }

    const size_t base = ((size_t)b * D_ + h * N_) * L_;
    const float* Vb = V + base;
    float* Ob = Om + base;
    const int p0 = y * W_ + x0;

    for (int n = 0; n < N_; ++n) {
        const float* Vr = Vb + (size_t)n * L_;
        float a0 = 0.f, a1 = 0.f, a2 = 0.f, a3 = 0.f;
#pragma unroll
        for (int dy = 0; dy < 3; ++dy) {
            const int r = y + dy - 1;
            if (r < 0 || r >= H_) continue;
            const float* row = Vr + r * W_ + x0;
            const float4 c = *(const float4*)row;
            const float vm = (x0 > 0)      ? row[-1] : 0.f;
            const float vp = (x0 + 4 < W_) ? row[4]  : 0.f;
            const float vl[6] = {vm, c.x, c.y, c.z, c.w, vp};
#pragma unroll
            for (int kw = 0; kw < 3; ++kw) {
                const int k = dy * 3 + kw;
                a0 = fmaf(w[k][0], vl[0 + kw], a0);
                a1 = fmaf(w[k][1], vl[1 + kw], a1);
                a2 = fmaf(w[k][2], vl[2 + kw], a2);
                a3 = fmaf(w[k][3], vl[3 + kw], a3);
            }
        }
        *(float4*)(Ob + (size_t)n * L_ + p0) = make_float4(a0, a1, a2, a3);
    }
}

// ---------------------------------------------------------------------------
// Kernel 4: out = Wproj @ out_mid (same structure as kernel 1, single W)
// ---------------------------------------------------------------------------
__global__ __launch_bounds__(256) void gemm_proj_kernel(
    const float* __restrict__ Xm, const float* __restrict__ Wp,
    float* __restrict__ Out)
{
    __shared__ float xs[16][64];
    __shared__ float wps[16][64];

    const int b  = blockIdx.z;
    const int d0 = blockIdx.y * 64;
    const int l0 = blockIdx.x * 64;
    const int tid = threadIdx.x;
    const int tx = tid & 15;
    const int ty = tid >> 4;

    const float* xb = Xm + (size_t)b * D_ * L_;

    float acc[4][4] = {{0.f}};

    const int xr = tid >> 4;
    const int xc = (tid & 15) * 4;
    const int wr = tid >> 2;
    const int wc = (tid & 3) * 4;

    for (int c0 = 0; c0 < D_; c0 += 16) {
        float4 xv = *(const float4*)(xb + (size_t)(c0 + xr) * L_ + (l0 + xc));
        float4 wv = *(const float4*)(Wp + (d0 + wr) * D_ + (c0 + wc));

        __syncthreads();
        *(float4*)&xs[xr][xc] = xv;
        wps[wc + 0][wr] = wv.x; wps[wc + 1][wr] = wv.y;
        wps[wc + 2][wr] = wv.z; wps[wc + 3][wr] = wv.w;
        __syncthreads();

#pragma unroll
        for (int c = 0; c < 16; ++c) {
            float4 a  = *(const float4*)&xs[c][tx * 4];
            float4 bw = *(const float4*)&wps[c][ty * 4];
            const float aj[4]  = {a.x, a.y, a.z, a.w};
            const float bwj[4] = {bw.x, bw.y, bw.z, bw.w};
#pragma unroll
            for (int i = 0; i < 4; ++i)
#pragma unroll
                for (int j = 0; j < 4; ++j)
                    acc[i][j] = fmaf(bwj[i], aj[j], acc[i][j]);
        }
    }

#pragma unroll
    for (int i = 0; i < 4; ++i) {
        const int d = d0 + ty * 4 + i;
        const size_t off = ((size_t)b * D_ + d) * L_ + l0 + tx * 4;
        *(float4*)(Out + off) = make_float4(acc[i][0], acc[i][1], acc[i][2], acc[i][3]);
    }
}

// ---------------------------------------------------------------------------
extern "C" void kernel_launch(void* const* d_in, const int* in_sizes, int n_in,
                              void* d_out, int out_size, void* d_ws, size_t ws_size,
                              hipStream_t stream)
{
    const float* x       = (const float*)d_in[0];
    const float* q       = (const float*)d_in[1];
    const float* Wk      = (const float*)d_in[2];
    const float* Wv      = (const float*)d_in[3];
    const float* pos_emb = (const float*)d_in[4];
    const float* Wlin    = (const float*)d_in[5];
    const float* Wproj   = (const float*)d_in[6];
    float* out = (float*)d_out;

    const size_t planeN = (size_t)B_ * D_ * L_;   // 12,845,056 floats
    float* Ko = (float*)d_ws;
    float* Vo = Ko + planeN;
    float* S  = Vo + planeN;
    float* Om = Ko;   // K dead after qk_s; reuse its region for out_mid

    // 1. K,V projection GEMMs (fused)
    gemm_kv_kernel<<<dim3(L_ / 64, D_ / 64, B_), 256, 0, stream>>>(x, Wk, Wv, Ko, Vo);

    // 2. S = q . K per head/position
    qk_s_kernel<<<dim3(L_ / 64, HEADS_, B_), 64, 0, stream>>>(Ko, q, S);

    // 3. softmax over 3x3 window + weighted V gather
    attend_kernel<<<dim3((B_ * HEADS_ * 784) / 256), 256, 0, stream>>>(
        S, Vo, pos_emb, Wlin, Om);

    // 4. output projection
    gemm_proj_kernel<<<dim3(L_ / 64, D_ / 64, B_), 256, 0, stream>>>(Om, Wproj, out);
}